// Round 3
// baseline (1500.229 us; speedup 1.0000x reference)
//
#include <hip/hip_runtime.h>
#include <cmath>

#define CH 32
#define NST 8
#define LSEQ 128

// ---------------------------------------------------------------------------
// Kernel 1: per-(b,c) mean+max over the contiguous 512*512 spatial slice.
// 1024 blocks (one per slice) x 256 threads, float4 loads, 2x unrolled for MLP.
// ---------------------------------------------------------------------------
__global__ __launch_bounds__(256) void reduce_mean_max(const float* __restrict__ in,
                                                       float* __restrict__ avg_out,
                                                       float* __restrict__ max_out) {
    const int slice = blockIdx.x;                       // b*128 + c
    const float4* p = (const float4*)(in + (size_t)slice * 262144);
    const int tid = threadIdx.x;

    float s0 = 0.f, s1 = 0.f, s2 = 0.f, s3 = 0.f;
    float s4 = 0.f, s5 = 0.f, s6 = 0.f, s7 = 0.f;
    float m0 = -INFINITY, m1 = -INFINITY;
    // 65536 float4 per slice; 2 loads per thread per iteration -> 128 iters
    for (int i = tid; i < 65536; i += 512) {
        float4 a = p[i];
        float4 b = p[i + 256];
        s0 += a.x; s1 += a.y; s2 += a.z; s3 += a.w;
        s4 += b.x; s5 += b.y; s6 += b.z; s7 += b.w;
        m0 = fmaxf(m0, fmaxf(fmaxf(a.x, a.y), fmaxf(a.z, a.w)));
        m1 = fmaxf(m1, fmaxf(fmaxf(b.x, b.y), fmaxf(b.z, b.w)));
    }
    float s = ((s0 + s1) + (s2 + s3)) + ((s4 + s5) + (s6 + s7));
    float m = fmaxf(m0, m1);
    // wave-64 butterfly
    for (int off = 1; off < 64; off <<= 1) {
        s += __shfl_xor(s, off, 64);
        m = fmaxf(m, __shfl_xor(m, off, 64));
    }
    __shared__ float ws_s[4], ws_m[4];
    const int wave = tid >> 6;
    if ((tid & 63) == 0) { ws_s[wave] = s; ws_m[wave] = m; }
    __syncthreads();
    if (tid == 0) {
        float S = (ws_s[0] + ws_s[1]) + (ws_s[2] + ws_s[3]);
        float M = fmaxf(fmaxf(ws_m[0], ws_m[1]), fmaxf(ws_m[2], ws_m[3]));
        avg_out[slice] = S * (1.0f / 262144.0f);
        max_out[slice] = M;
    }
}

// ---------------------------------------------------------------------------
// Kernel 2: the whole rest of the net. One block per batch (8 blocks, 256 thr).
// ---------------------------------------------------------------------------
__device__ __forceinline__ float siluf(float x) { return x / (1.0f + expf(-x)); }
__device__ __forceinline__ float softplusf(float x) {
    return fmaxf(x, 0.0f) + log1pf(expf(-fabsf(x)));
}

__global__ __launch_bounds__(256) void mamba_tail(
    const float* __restrict__ avg, const float* __restrict__ mx,
    const float* __restrict__ lin1_w, const float* __restrict__ lin1_b,
    const float* __restrict__ ln1_g, const float* __restrict__ ln1_b,
    const float* __restrict__ in_proj_w,
    const float* __restrict__ conv_w, const float* __restrict__ conv_b,
    const float* __restrict__ conv_bw, const float* __restrict__ conv_bb,
    const float* __restrict__ x_proj_w, const float* __restrict__ x_proj_bw,
    const float* __restrict__ dt_proj_w, const float* __restrict__ dt_proj_bias,
    const float* __restrict__ dt_proj_bw, const float* __restrict__ dt_proj_bbias,
    const float* __restrict__ A_log, const float* __restrict__ A_b_log,
    const float* __restrict__ Dp, const float* __restrict__ D_b,
    const float* __restrict__ mnorm_g, const float* __restrict__ mnorm_b,
    const float* __restrict__ out_proj_w,
    const float* __restrict__ lin2_w, const float* __restrict__ lin2_b,
    float* __restrict__ out) {

    __shared__ float s_avg[LSEQ], s_mx[LSEQ];
    __shared__ float s_h[LSEQ][CH];     // after ln1 (dead after in_proj)
    __shared__ float s_x[LSEQ][CH];
    __shared__ float s_z[LSEQ][CH];
    __shared__ float s_xc[LSEQ][CH];    // conv+silu output (branch coords)
    __shared__ float s_dtpre[LSEQ][2];
    __shared__ float s_dt[LSEQ][CH];
    __shared__ float s_B[LSEQ][NST];
    __shared__ float s_C[LSEQ][NST];
    __shared__ float s_y[LSEQ][CH];     // yf then += yb (original coords)

    const int b = blockIdx.x;
    const int tid = threadIdx.x;

    if (tid < LSEQ) {
        s_avg[tid] = avg[b * LSEQ + tid];
        s_mx[tid]  = mx[b * LSEQ + tid];
    }
    __syncthreads();

    // ---- lin1 + layernorm -> s_h --------------------------------------
    {
        const int c = tid & 31, row0 = tid >> 5;
        const float w0 = lin1_w[c * 2 + 0], w1 = lin1_w[c * 2 + 1], bb = lin1_b[c];
        const float g = ln1_g[c], be = ln1_b[c];
        for (int l = row0; l < LSEQ; l += 8) {
            float v = s_avg[l] * w0 + s_mx[l] * w1 + bb;
            float mu = v;
            for (int off = 1; off < 32; off <<= 1) mu += __shfl_xor(mu, off, 32);
            mu *= (1.0f / 32.0f);
            float d = v - mu;
            float var = d * d;
            for (int off = 1; off < 32; off <<= 1) var += __shfl_xor(var, off, 32);
            var *= (1.0f / 32.0f);
            s_h[l][c] = d * (1.0f / sqrtf(var + 1e-5f)) * g + be;
        }
    }
    __syncthreads();

    // ---- in_proj: xz = h @ W.T ; x = xz[:, :32], z = xz[:, 32:] -------
    for (int idx = tid; idx < LSEQ * 64; idx += 256) {
        const int l = idx >> 6, j = idx & 63;
        const float* w = in_proj_w + j * CH;
        float acc = 0.f;
        #pragma unroll
        for (int c = 0; c < CH; ++c) acc += s_h[l][c] * w[c];
        if (j < CH) s_x[l][j] = acc; else s_z[l][j - CH] = acc;
    }
    __syncthreads();

    // ---- two branches (fwd, bwd-on-reversed-sequence) ------------------
    for (int br = 0; br < 2; ++br) {
        const float* cw  = br ? conv_bw : conv_w;
        const float* cb  = br ? conv_bb : conv_b;
        const float* xpw = br ? x_proj_bw : x_proj_w;
        const float* dtw = br ? dt_proj_bw : dt_proj_w;
        const float* dtb = br ? dt_proj_bbias : dt_proj_bias;
        const float* Al  = br ? A_b_log : A_log;
        const float* Dv  = br ? D_b : Dp;

        // causal depthwise conv + silu  (branch coords: pos l = orig seq(l))
        for (int idx = tid; idx < LSEQ * CH; idx += 256) {
            const int l = idx >> 5, c = idx & 31;
            float acc = cb[c];
            #pragma unroll
            for (int k = 0; k < 4; ++k) {
                const int lp = l - 3 + k;
                if (lp >= 0) {
                    const int o = br ? (LSEQ - 1 - lp) : lp;
                    acc += cw[c * 4 + k] * s_x[o][c];
                }
            }
            s_xc[l][c] = siluf(acc);
        }
        __syncthreads();

        // x_proj: xdbl[l][0:2]=dt_pre, [2:10]=B, [10:18]=C
        for (int idx = tid; idx < LSEQ * 18; idx += 256) {
            const int l = idx / 18, j = idx - l * 18;
            const float* w = xpw + j * CH;
            float acc = 0.f;
            #pragma unroll
            for (int c = 0; c < CH; ++c) acc += s_xc[l][c] * w[c];
            if (j < 2)       s_dtpre[l][j] = acc;
            else if (j < 10) s_B[l][j - 2] = acc;
            else             s_C[l][j - 10] = acc;
        }
        __syncthreads();

        // dt = softplus(dt_pre @ dt_proj_w.T + bias)
        for (int idx = tid; idx < LSEQ * CH; idx += 256) {
            const int l = idx >> 5, d = idx & 31;
            const float pre = s_dtpre[l][0] * dtw[d * 2] +
                              s_dtpre[l][1] * dtw[d * 2 + 1] + dtb[d];
            s_dt[l][d] = softplusf(pre);
        }
        __syncthreads();

        // selective scan: thread = (d, n); reduce over n via shfl width 8
        {
            const int d = tid >> 3, n = tid & 7;
            const float A = -expf(Al[d * NST + n]);
            const float Dd = Dv[d];
            float h = 0.0f;
            for (int l = 0; l < LSEQ; ++l) {
                const float dtv = s_dt[l][d];
                const float xv  = s_xc[l][d];
                const float dA  = expf(dtv * A);
                h = dA * h + dtv * xv * s_B[l][n];
                float p = h * s_C[l][n];
                p += __shfl_xor(p, 1, 8);
                p += __shfl_xor(p, 2, 8);
                p += __shfl_xor(p, 4, 8);
                if (n == 0) {
                    float yv = p + xv * Dd;
                    const int o = br ? (LSEQ - 1 - l) : l;   // original position
                    const float zv = s_z[o][d];
                    yv *= siluf(zv);
                    if (br) s_y[o][d] += yv; else s_y[o][d] = yv;
                }
            }
        }
        __syncthreads();
    }

    // ---- mnorm layernorm + folded out_proj/lin2 + tanh -----------------
    {
        const int c = tid & 31, row0 = tid >> 5;
        const float g = mnorm_g[c], be = mnorm_b[c];
        // v[c] = 0.5 * sum_d lin2_w[d] * out_proj_w[d][c]   (linear fold)
        float vproj = 0.0f;
        #pragma unroll
        for (int d = 0; d < CH; ++d) vproj += lin2_w[d] * out_proj_w[d * CH + c];
        vproj *= 0.5f;
        const float l2b = lin2_b[0];
        for (int l = row0; l < LSEQ; l += 8) {
            float v = s_y[l][c];
            float mu = v;
            for (int off = 1; off < 32; off <<= 1) mu += __shfl_xor(mu, off, 32);
            mu *= (1.0f / 32.0f);
            float d0 = v - mu;
            float var = d0 * d0;
            for (int off = 1; off < 32; off <<= 1) var += __shfl_xor(var, off, 32);
            var *= (1.0f / 32.0f);
            const float yln = d0 * (1.0f / sqrtf(var + 1e-5f)) * g + be;
            float t = yln * vproj;
            for (int off = 1; off < 32; off <<= 1) t += __shfl_xor(t, off, 32);
            if (c == 0) out[b * LSEQ + l] = tanhf(t + l2b) * 0.5f + 1.0f;
        }
    }
}

// ---------------------------------------------------------------------------
extern "C" void kernel_launch(void* const* d_in, const int* in_sizes, int n_in,
                              void* d_out, int out_size, void* d_ws, size_t ws_size,
                              hipStream_t stream) {
    const float* input = (const float*)d_in[0];
    float* ws  = (float*)d_ws;
    float* avg = ws;          // 1024 floats
    float* mxp = ws + 1024;   // 1024 floats

    reduce_mean_max<<<1024, 256, 0, stream>>>(input, avg, mxp);

    mamba_tail<<<8, 256, 0, stream>>>(
        avg, mxp,
        (const float*)d_in[1],  (const float*)d_in[2],   // lin1_w, lin1_b
        (const float*)d_in[3],  (const float*)d_in[4],   // ln1_g, ln1_b
        (const float*)d_in[5],                           // in_proj_w
        (const float*)d_in[6],  (const float*)d_in[7],   // conv_w, conv_b
        (const float*)d_in[8],  (const float*)d_in[9],   // conv_b_w, conv_b_b
        (const float*)d_in[10], (const float*)d_in[11],  // x_proj_w, x_proj_b_w
        (const float*)d_in[12], (const float*)d_in[13],  // dt_proj_w, dt_proj_bias
        (const float*)d_in[14], (const float*)d_in[15],  // dt_proj_b_w, dt_proj_b_bias
        (const float*)d_in[16], (const float*)d_in[17],  // A_log, A_b_log
        (const float*)d_in[18], (const float*)d_in[19],  // Dp, D_b
        (const float*)d_in[20], (const float*)d_in[21],  // mnorm_g, mnorm_b
        (const float*)d_in[22],                          // out_proj_w
        (const float*)d_in[23], (const float*)d_in[24],  // lin2_w, lin2_b
        (float*)d_out);
}